// Round 15
// baseline (271.270 us; speedup 1.0000x reference)
//
#include <hip/hip_runtime.h>

#define BN_EPS 1e-5f
#define LOG2E 1.44269504f
// B=4, C=64, H=W=64, N=4096, D=8

typedef __attribute__((ext_vector_type(8))) short short8v;
typedef __attribute__((ext_vector_type(4))) float float4v;
typedef __attribute__((ext_vector_type(4))) unsigned uint4v;
typedef __attribute__((ext_vector_type(2))) unsigned uint2v;

__device__ inline unsigned short f2bf(float f) {
    unsigned u = __float_as_uint(f);
    u += 0x7fffu + ((u >> 16) & 1u);   // round-to-nearest-even
    return (unsigned short)(u >> 16);
}

__device__ inline float fexp2(float x) { return __builtin_amdgcn_exp2f(x); }

__device__ inline unsigned cvtpk_bf16(float lo, float hi) {
    unsigned r;
    asm("v_cvt_pk_bf16_f32 %0, %1, %2" : "=v"(r) : "v"(lo), "v"(hi));
    return r;
}

// BN stats from per-(b,c) partials: ps[0..255]=sum, ps[256..511]=sumsq
__device__ inline void bn_from_ps(const float* __restrict__ ps, int c,
                                  float& mean, float& rstd) {
    float S  = (ps[c]     + ps[64+c])  + (ps[128+c] + ps[192+c]);
    float S2 = (ps[256+c] + ps[320+c]) + (ps[384+c] + ps[448+c]);
    mean = S / 16384.f;
    float var = S2 / 16384.f - mean*mean;
    rstd = rsqrtf(fmaxf(var, 0.f) + BN_EPS);
}

// async global->LDS, 16B per lane; LDS dest = uniform base + lane*16
#define GLOAD_LDS(gp, lp) __builtin_amdgcn_global_load_lds( \
    (const __attribute__((address_space(1))) void*)(gp),    \
    (__attribute__((address_space(3))) void*)(lp), 16, 0, 0)

__global__ void conv1_kernel(const float* __restrict__ x, const float* __restrict__ w,
                             float* __restrict__ out) {
    int idx = blockIdx.x * 256 + threadIdx.x;   // [b][o][y][x]
    int xx = idx & 63, y = (idx >> 6) & 63, o = (idx >> 12) & 63, b = idx >> 18;
    float acc = 0.f;
    #pragma unroll
    for (int i = 0; i < 3; ++i) {
        #pragma unroll
        for (int dy = 0; dy < 3; ++dy) {
            int gy = y + dy - 1;
            if (gy < 0 || gy > 63) continue;
            #pragma unroll
            for (int dx = 0; dx < 3; ++dx) {
                int gx = xx + dx - 1;
                if (gx < 0 || gx > 63) continue;
                acc += w[o*27 + i*9 + dy*3 + dx] * x[(b*3 + i)*4096 + gy*64 + gx];
            }
        }
    }
    out[idx] = acc;
}

// partial sums per (b,c): 256 blocks
__global__ void stats_part_kernel(const float* __restrict__ t, float* __restrict__ ps) {
    int bc = blockIdx.x;
    int tid = threadIdx.x;
    const float4* p4 = (const float4*)(t + (size_t)bc * 4096);
    float s = 0.f, s2 = 0.f;
    for (int n = tid; n < 1024; n += 256) {
        float4 v = p4[n];
        s  += (v.x + v.y) + (v.z + v.w);
        s2 += (v.x*v.x + v.y*v.y) + (v.z*v.z + v.w*v.w);
    }
    #pragma unroll
    for (int off = 32; off > 0; off >>= 1) {
        s  += __shfl_down(s, off);
        s2 += __shfl_down(s2, off);
    }
    __shared__ float ls[8];
    int wv = tid >> 6, ln = tid & 63;
    if (ln == 0) { ls[wv] = s; ls[4+wv] = s2; }
    __syncthreads();
    if (tid == 0) {
        ps[bc]       = ls[0]+ls[1]+ls[2]+ls[3];
        ps[256 + bc] = ls[4]+ls[5]+ls[6]+ls[7];
    }
}

// BN+ReLU on t1 + transpose + bf16: t1 fp32 [b][c][n] -> xT bf16 [b][n][c]
__global__ __launch_bounds__(256) void bnrelu_t_kernel(const float* __restrict__ t,
        const float* __restrict__ ps, const float* __restrict__ g,
        const float* __restrict__ bb, unsigned short* __restrict__ xT) {
    int b = blockIdx.y, n0 = blockIdx.x * 64;
    int tid = threadIdx.x;
    int ln = tid & 63, r0 = tid >> 6;
    __shared__ float xs[64][65];
    for (int c = r0; c < 64; c += 4) {
        float mean, rstd;
        bn_from_ps(ps, c, mean, rstd);
        float v = t[(size_t)(b*64 + c)*4096 + n0 + ln];
        v = (v - mean) * (rstd * g[c]) + bb[c];
        xs[c][ln] = v > 0.f ? v : 0.f;
    }
    __syncthreads();
    int n_l = tid >> 2, cg = tid & 3;   // thread writes 16 c of pixel n0+n_l
    int c0 = cg * 16;
    uint4v pk0, pk1;
    #pragma unroll
    for (int e = 0; e < 4; ++e) {
        pk0[e] = cvtpk_bf16(xs[c0 + 2*e][n_l],     xs[c0 + 2*e + 1][n_l]);
        pk1[e] = cvtpk_bf16(xs[c0 + 8 + 2*e][n_l], xs[c0 + 8 + 2*e + 1][n_l]);
    }
    unsigned short* op = xT + ((size_t)b*4096 + n0 + n_l) * 64 + c0;
    *(uint4v*)op = pk0;
    *(uint4v*)(op + 8) = pk1;
}

// c2w [o][ci][3][3] fp32 -> wT [tap][o][ci] bf16
__global__ void wprep_kernel(const float* __restrict__ w, unsigned short* __restrict__ wT) {
    int idx = blockIdx.x * 256 + threadIdx.x;   // 36864
    int ci = idx & 63, o = (idx >> 6) & 63, t = idx >> 12;
    wT[idx] = f2bf(w[o*576 + ci*9 + t]);
}

// conv2 as implicit GEMM on MFMA (see r9 notes)
__global__ __launch_bounds__(512) void conv2_mfma_kernel(
        const unsigned short* __restrict__ xT, const unsigned short* __restrict__ wT,
        float* __restrict__ out) {
    int b = blockIdx.y;
    int y = blockIdx.x;
    int tid = threadIdx.x;
    int w8 = tid >> 6, ln = tid & 63;
    int ot = w8 & 3, nh = w8 >> 2;
    int li = ln & 15, g = ln >> 4;
    int obase = ot * 16;

    const unsigned short* xb = xT + (size_t)b * 4096 * 64;
    const short8v zf = {0,0,0,0,0,0,0,0};

    short8v af0[9], af1[9];
    #pragma unroll
    for (int t = 0; t < 9; ++t) {
        const unsigned short* wrow = wT + ((size_t)t*64 + obase + li) * 64 + 8*g;
        af0[t] = *(const short8v*)(wrow);
        af1[t] = *(const short8v*)(wrow + 32);
    }

    float4v acc0 = {0.f,0.f,0.f,0.f}, acc1 = {0.f,0.f,0.f,0.f};
    int nA = y*64 + nh*32 + li;
    int nB = nA + 16;
    int xA = nA & 63, xB = nB & 63;

    #pragma unroll
    for (int t = 0; t < 9; ++t) {
        int dy = t/3 - 1, dx = (t%3) - 1;
        bool rowok = (y + dy >= 0) && (y + dy <= 63);
        int sh = dy*64 + dx;
        bool okA = rowok && (xA + dx >= 0) && (xA + dx <= 63);
        bool okB = rowok && (xB + dx >= 0) && (xB + dx <= 63);
        const unsigned short* xrA = xb + (size_t)(okA ? nA + sh : nA) * 64 + 8*g;
        const unsigned short* xrB = xb + (size_t)(okB ? nB + sh : nB) * 64 + 8*g;
        short8v bA0 = *(const short8v*)(xrA);
        short8v bA1 = *(const short8v*)(xrA + 32);
        short8v bB0 = *(const short8v*)(xrB);
        short8v bB1 = *(const short8v*)(xrB + 32);
        if (!okA) { bA0 = zf; bA1 = zf; }
        if (!okB) { bB0 = zf; bB1 = zf; }
        acc0 = __builtin_amdgcn_mfma_f32_16x16x32_bf16(af0[t], bA0, acc0, 0, 0, 0);
        acc0 = __builtin_amdgcn_mfma_f32_16x16x32_bf16(af1[t], bA1, acc0, 0, 0, 0);
        acc1 = __builtin_amdgcn_mfma_f32_16x16x32_bf16(af0[t], bB0, acc1, 0, 0, 0);
        acc1 = __builtin_amdgcn_mfma_f32_16x16x32_bf16(af1[t], bB1, acc1, 0, 0, 0);
    }

    #pragma unroll
    for (int r = 0; r < 4; ++r) {
        int o = obase + 4*g + r;
        size_t base = ((size_t)(b*64 + o)) * 4096;
        out[base + nA] = acc0[r];
        out[base + nB] = acc1[r];
    }
}

// qkv as MFMA, no LDS (per attention block; BN2+ReLU folded when bnflag).
// Verified r10/r12 operand layout.
__global__ __launch_bounds__(256) void qkv_mfma_kernel(const float* __restrict__ h,
    const float* __restrict__ qw, const float* __restrict__ qb,
    const float* __restrict__ kw, const float* __restrict__ kb,
    const float* __restrict__ vw, const float* __restrict__ vb,
    const float* __restrict__ ps, const float* __restrict__ g2,
    const float* __restrict__ b2, int a, int bnflag,
    unsigned short* __restrict__ qT, unsigned short* __restrict__ kT,
    unsigned short* __restrict__ vB) {
    int b = blockIdx.y;
    int tid = threadIdx.x;
    int w = tid >> 6, ln = tid & 63;
    int li = ln & 15, g = ln >> 4;
    int n = blockIdx.x * 64 + w * 16 + li;

    const float* hb = h + (size_t)b * 64 * 4096 + n;

    short8v wf[5][2];
    {
        const float* src0;
        float scale = 1.f;
        if (li < 8) { src0 = qw + a*512 + li*64; scale = LOG2E; }
        else        { src0 = kw + a*512 + (li-8)*64; }
        #pragma unroll
        for (int kh = 0; kh < 2; ++kh) {
            uint4v pk;
            #pragma unroll
            for (int e = 0; e < 4; ++e)
                pk[e] = cvtpk_bf16(src0[kh*32 + 8*g + 2*e] * scale,
                                   src0[kh*32 + 8*g + 2*e + 1] * scale);
            wf[0][kh] = __builtin_bit_cast(short8v, pk);
        }
        #pragma unroll
        for (int rt = 1; rt < 5; ++rt) {
            const float* src = vw + a*4096 + (rt*16 - 16 + li)*64;
            #pragma unroll
            for (int kh = 0; kh < 2; ++kh) {
                uint4v pk;
                #pragma unroll
                for (int e = 0; e < 4; ++e)
                    pk[e] = cvtpk_bf16(src[kh*32 + 8*g + 2*e],
                                       src[kh*32 + 8*g + 2*e + 1]);
                wf[rt][kh] = __builtin_bit_cast(short8v, pk);
            }
        }
    }

    float4v acc0, acc1, acc2, acc3, acc4;
    {
        int r4 = 4*g;
        #pragma unroll
        for (int r = 0; r < 4; ++r) {
            int row = r4 + r;
            acc0[r] = (row < 8) ? qb[a*8 + row] * LOG2E : kb[a*8 + row - 8];
            acc1[r] = vb[a*64 + 0  + row];
            acc2[r] = vb[a*64 + 16 + row];
            acc3[r] = vb[a*64 + 32 + row];
            acc4[r] = vb[a*64 + 48 + row];
        }
    }

    short8v hf0, hf1;
    #pragma unroll
    for (int kh = 0; kh < 2; ++kh) {
        uint4v pk;
        #pragma unroll
        for (int e = 0; e < 4; ++e) {
            int c0 = kh*32 + 8*g + 2*e;
            float x0 = hb[(size_t)c0 * 4096];
            float x1 = hb[(size_t)(c0 + 1) * 4096];
            if (bnflag) {
                float m0, r0, m1, r1;
                bn_from_ps(ps, c0, m0, r0);
                bn_from_ps(ps, c0 + 1, m1, r1);
                x0 = (x0 - m0) * (r0 * g2[c0]) + b2[c0];
                x1 = (x1 - m1) * (r1 * g2[c0+1]) + b2[c0+1];
                x0 = x0 > 0.f ? x0 : 0.f;
                x1 = x1 > 0.f ? x1 : 0.f;
            }
            pk[e] = cvtpk_bf16(x0, x1);
        }
        if (kh == 0) hf0 = __builtin_bit_cast(short8v, pk);
        else         hf1 = __builtin_bit_cast(short8v, pk);
    }

    acc0 = __builtin_amdgcn_mfma_f32_16x16x32_bf16(wf[0][0], hf0, acc0, 0, 0, 0);
    acc0 = __builtin_amdgcn_mfma_f32_16x16x32_bf16(wf[0][1], hf1, acc0, 0, 0, 0);
    acc1 = __builtin_amdgcn_mfma_f32_16x16x32_bf16(wf[1][0], hf0, acc1, 0, 0, 0);
    acc1 = __builtin_amdgcn_mfma_f32_16x16x32_bf16(wf[1][1], hf1, acc1, 0, 0, 0);
    acc2 = __builtin_amdgcn_mfma_f32_16x16x32_bf16(wf[2][0], hf0, acc2, 0, 0, 0);
    acc2 = __builtin_amdgcn_mfma_f32_16x16x32_bf16(wf[2][1], hf1, acc2, 0, 0, 0);
    acc3 = __builtin_amdgcn_mfma_f32_16x16x32_bf16(wf[3][0], hf0, acc3, 0, 0, 0);
    acc3 = __builtin_amdgcn_mfma_f32_16x16x32_bf16(wf[3][1], hf1, acc3, 0, 0, 0);
    acc4 = __builtin_amdgcn_mfma_f32_16x16x32_bf16(wf[4][0], hf0, acc4, 0, 0, 0);
    acc4 = __builtin_amdgcn_mfma_f32_16x16x32_bf16(wf[4][1], hf1, acc4, 0, 0, 0);

    {
        uint2v pk;
        pk[0] = cvtpk_bf16(acc0[0], acc0[1]);
        pk[1] = cvtpk_bf16(acc0[2], acc0[3]);
        if (g < 2) *(uint2v*)(qT + ((size_t)b*4096 + n)*8 + 4*g) = pk;
        else       *(uint2v*)(kT + ((size_t)b*4096 + n)*8 + 4*g - 8) = pk;
    }
    #pragma unroll
    for (int r = 0; r < 4; ++r) {
        int row = 4*g + r;
        vB[((size_t)(b*64 + 0  + row))*4096 + n] = f2bf(acc1[r]);
        vB[((size_t)(b*64 + 16 + row))*4096 + n] = f2bf(acc2[r]);
        vB[((size_t)(b*64 + 32 + row))*4096 + n] = f2bf(acc3[r]);
        vB[((size_t)(b*64 + 48 + row))*4096 + n] = f2bf(acc4[r]);
    }
}

// Single-pass MFMA flash, no online max (scores provably small — see r7).
// 128-j tiles (8 iters, half the barriers of r14's 64-j version).
// K/V staged via async global_load_lds, double-buffered, counted vmcnt.
// V layout [64 c][16 chunks x 8], physical chunk p = logical ^ (c&7),
// applied by pre-swizzling the GLOBAL source (LDS dest stays linear).
// T5: setprio(1) around the 16-MFMA PV cluster.
__global__ __launch_bounds__(256) void flash_split_kernel(
    const unsigned short* __restrict__ qT, const unsigned short* __restrict__ kT,
    const unsigned short* __restrict__ vB,
    float* __restrict__ accO0, float* __restrict__ accP,
    float* __restrict__ lP) {
    int b = blockIdx.z;
    int js = blockIdx.y;
    int tid = threadIdx.x;
    int w = tid >> 6, ln = tid & 63;
    int li = ln & 15, g = ln >> 4;
    int i0 = blockIdx.x * 64 + w * 16;

    const unsigned short* qTb = qT + (size_t)b * 4096 * 8;
    const unsigned short* kTb = kT + (size_t)b * 4096 * 8;
    const unsigned short* vBb = vB + (size_t)b * 64 * 4096;

    __shared__ unsigned short kbuf[2][1024];   // [128 j][8 d]
    __shared__ unsigned short vbuf[2][8192];   // [64 c][16 chunks x 8], swizzled

    const short8v zf = {0,0,0,0,0,0,0,0};
    short8v qf = zf;
    if (g == 0) qf = *(const short8v*)(qTb + (size_t)(i0 + li) * 8);

    int jp = 2*li - (li & 3);    // f0(li)
    int vrow = li * 128;
    // physical chunk byte-offsets (shorts) for logical chunk jg*4+g
    int pc0 = ((0 + g) ^ (li & 7)) * 8;
    int pc1 = ((4 + g) ^ (li & 7)) * 8;
    int pc2 = ((8 + g) ^ (li & 7)) * 8;
    int pc3 = ((12 + g) ^ (li & 7)) * 8;

    // staging source offsets: 4 V-gloads per wave (q = 0..3)
    size_t vsrc0, vsrc1, vsrc2, vsrc3;
    {
        int cc0 = w*16 + 0 + (ln >> 4);
        int cc1 = w*16 + 4 + (ln >> 4);
        int cc2 = w*16 + 8 + (ln >> 4);
        int cc3 = w*16 + 12 + (ln >> 4);
        vsrc0 = (size_t)cc0 * 4096 + (size_t)(((ln & 15) ^ (cc0 & 7)) * 8);
        vsrc1 = (size_t)cc1 * 4096 + (size_t)(((ln & 15) ^ (cc1 & 7)) * 8);
        vsrc2 = (size_t)cc2 * 4096 + (size_t)(((ln & 15) ^ (cc2 & 7)) * 8);
        vsrc3 = (size_t)cc3 * 4096 + (size_t)(((ln & 15) ^ (cc3 & 7)) * 8);
    }

    float lsum = 0.f;
    float4v acc0 = {0.f,0.f,0.f,0.f}, acc1 = {0.f,0.f,0.f,0.f};
    float4v acc2 = {0.f,0.f,0.f,0.f}, acc3 = {0.f,0.f,0.f,0.f};

    int jbase = js * 1024;

    // prologue: stage tile 0 into buffer 0
    if (w == 0) {
        GLOAD_LDS(kTb + (size_t)(jbase + ln) * 8,      &kbuf[0][0]);
        GLOAD_LDS(kTb + (size_t)(jbase + 64 + ln) * 8, &kbuf[0][512]);
    }
    GLOAD_LDS(vBb + vsrc0 + jbase, &vbuf[0][w*2048 + 0]);
    GLOAD_LDS(vBb + vsrc1 + jbase, &vbuf[0][w*2048 + 512]);
    GLOAD_LDS(vBb + vsrc2 + jbase, &vbuf[0][w*2048 + 1024]);
    GLOAD_LDS(vBb + vsrc3 + jbase, &vbuf[0][w*2048 + 1536]);

    for (int t = 0; t < 8; ++t) {
        int cur = t & 1;
        if (t < 7) {
            int j0n = jbase + (t + 1) * 128;
            if (w == 0) {
                GLOAD_LDS(kTb + (size_t)(j0n + ln) * 8,      &kbuf[cur ^ 1][0]);
                GLOAD_LDS(kTb + (size_t)(j0n + 64 + ln) * 8, &kbuf[cur ^ 1][512]);
            }
            GLOAD_LDS(vBb + vsrc0 + j0n, &vbuf[cur ^ 1][w*2048 + 0]);
            GLOAD_LDS(vBb + vsrc1 + j0n, &vbuf[cur ^ 1][w*2048 + 512]);
            GLOAD_LDS(vBb + vsrc2 + j0n, &vbuf[cur ^ 1][w*2048 + 1024]);
            GLOAD_LDS(vBb + vsrc3 + j0n, &vbuf[cur ^ 1][w*2048 + 1536]);
            // wait for PREVIOUS tile's stages only; keep this tile's in flight
            if (w == 0) asm volatile("s_waitcnt vmcnt(6)" ::: "memory");
            else        asm volatile("s_waitcnt vmcnt(4)" ::: "memory");
        } else {
            asm volatile("s_waitcnt vmcnt(0)" ::: "memory");
        }
        __builtin_amdgcn_s_barrier();   // buf[cur] staged by all waves

        const unsigned short* kb = &kbuf[cur][0];
        const unsigned short* vb = &vbuf[cur][0];

        // QK^T + softmax for 4 groups of 32 j -> P fragments
        short8v pf[4];
        #pragma unroll
        for (int m = 0; m < 4; ++m) {
            short8v k0 = *(const short8v*)(kb + (jp + m*32) * 8);
            short8v k1 = *(const short8v*)(kb + (jp + 4 + m*32) * 8);
            float4v s0 = {0.f,0.f,0.f,0.f}, s1 = {0.f,0.f,0.f,0.f};
            s0 = __builtin_amdgcn_mfma_f32_16x16x32_bf16(k0, qf, s0, 0, 0, 0);
            s1 = __builtin_amdgcn_mfma_f32_16x16x32_bf16(k1, qf, s1, 0, 0, 0);
            float p0 = fexp2(s0[0]), p1 = fexp2(s0[1]);
            float p2 = fexp2(s0[2]), p3 = fexp2(s0[3]);
            float p4 = fexp2(s1[0]), p5 = fexp2(s1[1]);
            float p6 = fexp2(s1[2]), p7 = fexp2(s1[3]);
            lsum += ((p0 + p1) + (p2 + p3)) + ((p4 + p5) + (p6 + p7));
            uint4v pi;
            pi[0] = cvtpk_bf16(p0, p1); pi[1] = cvtpk_bf16(p2, p3);
            pi[2] = cvtpk_bf16(p4, p5); pi[3] = cvtpk_bf16(p6, p7);
            pf[m] = __builtin_bit_cast(short8v, pi);
        }

        // PV: 4 channel-tiles x 4 j-groups
        __builtin_amdgcn_s_setprio(1);
        {
            const unsigned short* vr = vb + vrow;
            short8v v0 = *(const short8v*)(vr + pc0);
            short8v v1 = *(const short8v*)(vr + pc1);
            short8v v2 = *(const short8v*)(vr + pc2);
            short8v v3 = *(const short8v*)(vr + pc3);
            acc0 = __builtin_amdgcn_mfma_f32_16x16x32_bf16(v0, pf[0], acc0, 0, 0, 0);
            acc0 = __builtin_amdgcn_mfma_f32_16x16x32_bf16(v1, pf[1], acc0, 0, 0, 0);
            acc0 = __builtin_amdgcn_mfma_f32_16x16x32_bf16(v2, pf[2], acc0, 0, 0, 0);
            acc0 = __builtin_amdgcn_mfma_f32_16x16x32_bf16(v3, pf[3], acc0, 0, 0, 0);
        }
        {
            const unsigned short* vr = vb + 2048 + vrow;
            short8v v0 = *(const short8v*)(vr + pc0);
            short8v v1 = *(const short8v*)(vr + pc1);
            short8v v2 = *(const short8v*)(vr + pc2);
            short8v v3 = *(const short8v*)(vr + pc3);
            acc1 = __builtin_amdgcn_mfma_f32_16x16x32_bf16(v0, pf[0], acc1, 0, 0, 0);
            acc1 = __builtin_amdgcn_mfma_f32_16x16x32_bf16(v1, pf[1], acc1, 0, 0, 0);
            acc1 = __builtin_amdgcn_mfma_f32_16x16x32_bf16(v2, pf[2], acc1, 0, 0, 0);
            acc1 = __builtin_amdgcn_mfma_f32_16x16x32_bf16(v3, pf[3], acc1, 0, 0, 0);
        }
        {
            const unsigned short* vr = vb + 4096 + vrow;
            short8v v0 = *(const short8v*)(vr + pc0);
            short8v v1 = *(const short8v*)(vr + pc1);
            short8v v2 = *(const short8v*)(vr + pc2);
            short8v v3 = *(const short8v*)(vr + pc3);
            acc2 = __builtin_amdgcn_mfma_f32_16x16x32_bf16(v0, pf[0], acc2, 0, 0, 0);
            acc2 = __builtin_amdgcn_mfma_f32_16x16x32_bf16(v1, pf[1], acc2, 0, 0, 0);
            acc2 = __builtin_amdgcn_mfma_f32_16x16x32_bf16(v2, pf[2], acc2, 0, 0, 0);
            acc2 = __builtin_amdgcn_mfma_f32_16x16x32_bf16(v3, pf[3], acc2, 0, 0, 0);
        }
        {
            const unsigned short* vr = vb + 6144 + vrow;
            short8v v0 = *(const short8v*)(vr + pc0);
            short8v v1 = *(const short8v*)(vr + pc1);
            short8v v2 = *(const short8v*)(vr + pc2);
            short8v v3 = *(const short8v*)(vr + pc3);
            acc3 = __builtin_amdgcn_mfma_f32_16x16x32_bf16(v0, pf[0], acc3, 0, 0, 0);
            acc3 = __builtin_amdgcn_mfma_f32_16x16x32_bf16(v1, pf[1], acc3, 0, 0, 0);
            acc3 = __builtin_amdgcn_mfma_f32_16x16x32_bf16(v2, pf[2], acc3, 0, 0, 0);
            acc3 = __builtin_amdgcn_mfma_f32_16x16x32_bf16(v3, pf[3], acc3, 0, 0, 0);
        }
        __builtin_amdgcn_s_setprio(0);
        __builtin_amdgcn_s_barrier();   // all reads of buf[cur] done before re-stage
    }
    lsum += __shfl_xor(lsum, 16);
    lsum += __shfl_xor(lsum, 32);

    float* accO = (js == 0) ? accO0 : (accP + (size_t)(js - 1) * 1048576);
    int i = i0 + li;
    #pragma unroll
    for (int r = 0; r < 4; ++r) {
        int c = 4*g + r;
        accO[((size_t)(b*64 + c      )) * 4096 + i] = acc0[r];
        accO[((size_t)(b*64 + c + 16)) * 4096 + i] = acc1[r];
        accO[((size_t)(b*64 + c + 32)) * 4096 + i] = acc2[r];
        accO[((size_t)(b*64 + c + 48)) * 4096 + i] = acc3[r];
    }
    if (g == 0) {
        lP[(size_t)(b*4 + js)*4096 + i] = lsum;
    }
}

// Combine the four j-splits (exact simple addition), gamma/l and residual.
// BN+ReLU applied to hin when bnflag (first attention reads raw conv2 out).
__global__ void merge_kernel(float* __restrict__ acc0io, const float* __restrict__ accP,
                             const float* __restrict__ lP,
                             const float* __restrict__ hin,
                             const float* __restrict__ ps, const float* __restrict__ g2,
                             const float* __restrict__ b2, int bnflag,
                             const float* __restrict__ gammas, int a) {
    int idx = blockIdx.x * 256 + threadIdx.x;   // 262144 float4s
    int e0 = idx << 2;
    int b = e0 >> 18, i0 = e0 & 4095;
    int c = (e0 >> 12) & 63;
    float gamma = gammas[a];
    float4 l0 = *(const float4*)&lP[(size_t)(b*4 + 0)*4096 + i0];
    float4 l1 = *(const float4*)&lP[(size_t)(b*4 + 1)*4096 + i0];
    float4 l2 = *(const float4*)&lP[(size_t)(b*4 + 2)*4096 + i0];
    float4 l3 = *(const float4*)&lP[(size_t)(b*4 + 3)*4096 + i0];
    float4 a0 = ((const float4*)acc0io)[idx];
    float4 a1 = ((const float4*)accP)[idx];
    float4 a2 = ((const float4*)accP)[idx + 262144];
    float4 a3 = ((const float4*)accP)[idx + 524288];
    float4 hv = ((const float4*)hin)[idx];
    if (bnflag) {
        float m, r;
        bn_from_ps(ps, c, m, r);
        float rv = r * g2[c], bv = b2[c];
        hv.x = (hv.x - m) * rv + bv; hv.x = hv.x > 0.f ? hv.x : 0.f;
        hv.y = (hv.y - m) * rv + bv; hv.y = hv.y > 0.f ? hv.y : 0.f;
        hv.z = (hv.z - m) * rv + bv; hv.z = hv.z > 0.f ? hv.z : 0.f;
        hv.w = (hv.w - m) * rv + bv; hv.w = hv.w > 0.f ? hv.w : 0.f;
    }
    float4 o;
    #pragma unroll
    for (int t = 0; t < 4; ++t) {
        float l = ((const float*)&l0)[t] + ((const float*)&l1)[t]
                + ((const float*)&l2)[t] + ((const float*)&l3)[t];
        float num = ((const float*)&a0)[t] + ((const float*)&a1)[t]
                  + ((const float*)&a2)[t] + ((const float*)&a3)[t];
        ((float*)&o)[t] = num * (gamma / l) + ((const float*)&hv)[t];
    }
    ((float4*)acc0io)[idx] = o;
}

// FUSED: final merge (a=3) + output projection. No hout write needed.
__global__ __launch_bounds__(512) void merge_proj_kernel(
    const float* __restrict__ acc0p, const float* __restrict__ accP,
    const float* __restrict__ lP, const float* __restrict__ hin,
    const float* __restrict__ gammas,
    const float* __restrict__ ow, const float* __restrict__ ob,
    float* __restrict__ out) {
    int b = blockIdx.y, n0 = blockIdx.x * 64;
    int tid = threadIdx.x;
    int cq = tid >> 6, nl = tid & 63;
    int i = n0 + nl;
    float l = (lP[(size_t)(b*4 + 0)*4096 + i] + lP[(size_t)(b*4 + 1)*4096 + i])
            + (lP[(size_t)(b*4 + 2)*4096 + i] + lP[(size_t)(b*4 + 3)*4096 + i]);
    float rg = gammas[3] / l;
    float acc = 0.f;
    #pragma unroll
    for (int k = 0; k < 8; ++k) {
        int c = cq + 8*k;
        size_t off = ((size_t)(b*64 + c)) * 4096 + i;
        float num = (acc0p[off] + accP[off]) + (accP[off + 1048576] + accP[off + 2097152]);
        float o = num * rg + hin[off];
        acc += ow[c] * o;
    }
    __shared__ float red[8][64];
    red[cq][nl] = acc;
    __syncthreads();
    if (tid < 64) {
        float s = ((red[0][tid] + red[1][tid]) + (red[2][tid] + red[3][tid]))
                + ((red[4][tid] + red[5][tid]) + (red[6][tid] + red[7][tid])) + ob[0];
        out[(size_t)b*4096 + n0 + tid] = s;
    }
}

extern "C" void kernel_launch(void* const* d_in, const int* in_sizes, int n_in,
                              void* d_out, int out_size, void* d_ws, size_t ws_size,
                              hipStream_t stream) {
    const float* x    = (const float*)d_in[0];
    const float* c1w  = (const float*)d_in[1];
    const float* bn1g = (const float*)d_in[2];
    const float* bn1b = (const float*)d_in[3];
    const float* c2w  = (const float*)d_in[4];
    const float* bn2g = (const float*)d_in[5];
    const float* bn2b = (const float*)d_in[6];
    const float* qw   = (const float*)d_in[7];
    const float* qbb  = (const float*)d_in[8];
    const float* kw   = (const float*)d_in[9];
    const float* kbb  = (const float*)d_in[10];
    const float* vw   = (const float*)d_in[11];
    const float* vbb  = (const float*)d_in[12];
    const float* gam  = (const float*)d_in[13];
    const float* ow   = (const float*)d_in[14];
    const float* ob   = (const float*)d_in[15];
    float* out = (float*)d_out;

    float* t1 = (float*)d_ws;                       // [4][64][4096] f32
    float* t2 = t1 + 1048576;                       // [4][64][4096] f32
    unsigned short* qT = (unsigned short*)(t2 + 1048576);  // [4][4096][8] bf16
    unsigned short* kT = qT + 131072;               // [4][4096][8] bf16
    unsigned short* vB = kT + 131072;               // [4][64][4096] bf16
    float* accP  = (float*)(vB + 1048576);          // 3 x [4][64][4096] f32 (split 1..3)
    float* lP    = accP + 3*1048576;                // [4][4][4096]
    float* ps    = lP + 65536;                      // [512]
    unsigned short* wT = (unsigned short*)(ps + 512);   // [9][64][64] bf16
    unsigned short* xT = (unsigned short*)accP;     // [4][4096][64] bf16 (aliases accP)

    wprep_kernel<<<144, 256, 0, stream>>>(c2w, wT);
    conv1_kernel<<<4096, 256, 0, stream>>>(x, c1w, t1);
    stats_part_kernel<<<256, 256, 0, stream>>>(t1, ps);
    bnrelu_t_kernel<<<dim3(64,4), 256, 0, stream>>>(t1, ps, bn1g, bn1b, xT);
    conv2_mfma_kernel<<<dim3(64,4), 512, 0, stream>>>(xT, wT, t2);
    stats_part_kernel<<<256, 256, 0, stream>>>(t2, ps);
    // BN2+ReLU folded into qkv (a==0) B-load and merge (a==0) hin path.

    float* cur = t2; float* oth = t1;
    for (int a = 0; a < 4; ++a) {
        int bnflag = (a == 0) ? 1 : 0;
        qkv_mfma_kernel<<<dim3(64,4), 256, 0, stream>>>(cur, qw, qbb, kw, kbb, vw, vbb,
                                                        ps, bn2g, bn2b, a, bnflag,
                                                        qT, kT, vB);
        flash_split_kernel<<<dim3(64,4,4), 256, 0, stream>>>(qT, kT, vB, oth, accP, lP);
        if (a < 3) {
            merge_kernel<<<1024, 256, 0, stream>>>(oth, accP, lP, cur,
                                                   ps, bn2g, bn2b, bnflag, gam, a);
            float* tmp = cur; cur = oth; oth = tmp;
        } else {
            merge_proj_kernel<<<dim3(64,4), 512, 0, stream>>>(
                oth, accP, lP, cur, gam, ow, ob, out);
        }
    }
}